// Round 9
// baseline (236.047 us; speedup 1.0000x reference)
//
#include <hip/hip_runtime.h>

typedef _Float16 h8 __attribute__((ext_vector_type(8)));
typedef _Float16 h4 __attribute__((ext_vector_type(4)));
typedef __fp16 fp16x2 __attribute__((ext_vector_type(2)));
typedef float f32x4 __attribute__((ext_vector_type(4)));

#define NSEQ 2048
#define DMODEL 1024
#define HD 64
#define C2 0.1803368801111244f   // 0.125 * log2(e), folded into Wq/bq

// ---------------- workspace layout (bytes) ----------------
#define OFF_HPE  (size_t)0           // 4096x1024 f16 = 8MB
#define OFF_WQ   (size_t)8388608     // 1024x1024 f16 = 2MB (pre-scaled by C2)
#define OFF_WK   (size_t)10485760
#define OFF_WV   (size_t)12582912
#define OFF_WO   (size_t)14680064
#define OFF_Q    (size_t)16777216    // 4096x1024 f16 = 8MB (Q pre-scaled by C2)
#define OFF_K    (size_t)25165824
#define OFF_VT   (size_t)33554432    // [2][1024][2048] f16 = 8MB (V^T per head)
#define OFF_AO   (size_t)41943040    // 4096x1024 f16 = 8MB
#define OFF_PB   (size_t)50331648    // [2][2048] f32 (log2-domain bias)

#define GLL(g, l) __builtin_amdgcn_global_load_lds( \
    (const __attribute__((address_space(1))) unsigned int*)(const void*)(g), \
    (__attribute__((address_space(3))) unsigned int*)(l), 16, 0, 0)

// ---------------- fused prep kernel ----------------
__global__ void prep_kernel(const float* __restrict__ h, _Float16* __restrict__ hpe,
                            const float* __restrict__ w0, const float* __restrict__ w1,
                            const float* __restrict__ w2, const float* __restrict__ w3,
                            _Float16* __restrict__ d0, _Float16* __restrict__ d1,
                            _Float16* __restrict__ d2, _Float16* __restrict__ d3,
                            const float* __restrict__ probs, const float* __restrict__ pbs,
                            float* __restrict__ pb) {
    int idx = blockIdx.x * blockDim.x + threadIdx.x;
    if (idx < 524288) {
        int row = idx >> 7;
        int c8 = (idx & 127) * 8;
        int n = row & (NSEQ - 1);
        const float kL = -0.025952563241307517f;           // -log2(10000)/512
        const float kInv2Pi = 0.15915494309189535f;
        union { float4 f4[2]; float f[8]; } in;
        in.f4[0] = *(const float4*)&h[(size_t)row * DMODEL + c8];
        in.f4[1] = *(const float4*)&h[(size_t)row * DMODEL + c8 + 4];
        union { _Float16 hh[8]; uint4 u; } out;
        #pragma unroll
        for (int p = 0; p < 4; ++p) {
            int i2 = (c8 >> 1) + p;
            float div = __builtin_amdgcn_exp2f((float)i2 * kL);
            float rev = (float)n * div * kInv2Pi;
            float rf = __builtin_amdgcn_fractf(rev);
            float s = __builtin_amdgcn_sinf(rf);
            float c = __builtin_amdgcn_cosf(rf);
            out.hh[2 * p]     = (_Float16)(in.f[2 * p] + s);
            out.hh[2 * p + 1] = (_Float16)(in.f[2 * p + 1] + c);
        }
        *(uint4*)&hpe[(size_t)row * DMODEL + c8] = out.u;
    } else if (idx < 1572864) {
        int j = idx - 524288;
        int which = j >> 18, i2 = j & 262143;
        const float* s = which == 0 ? w0 : which == 1 ? w1 : which == 2 ? w2 : w3;
        _Float16* d    = which == 0 ? d0 : which == 1 ? d1 : which == 2 ? d2 : d3;
        float sc = which == 0 ? C2 : 1.0f;
        float4 v = ((const float4*)s)[i2];
        union { _Float16 hh[4]; uint2 u; } o;
        o.hh[0] = (_Float16)(v.x * sc); o.hh[1] = (_Float16)(v.y * sc);
        o.hh[2] = (_Float16)(v.z * sc); o.hh[3] = (_Float16)(v.w * sc);
        ((uint2*)d)[i2] = o.u;
    } else if (idx < 1576960) {
        int k = idx - 1572864;
        pb[k] = pbs[0] * log2f(probs[k] + 1e-8f);
    }
}

// ---------------- fused QKV GEMM: 128x128 tile, 2-phase double-buffered LDS ----------------
// grid 768 = 8 XCD x 96; byy: 0-7 -> Q (bias*C2), 8-15 -> K, 16-23 -> V^T.
__global__ __launch_bounds__(256) void gemm_qkv(
    const _Float16* __restrict__ A,
    const _Float16* __restrict__ Wqp, const _Float16* __restrict__ Wkp, const _Float16* __restrict__ Wvp,
    const float* __restrict__ bqp, const float* __restrict__ bkp, const float* __restrict__ bvp,
    _Float16* __restrict__ qb, _Float16* __restrict__ kb, _Float16* __restrict__ vt)
{
    __shared__ __align__(16) _Float16 As[2][128][64];   // 32KB
    __shared__ __align__(16) _Float16 Bs[2][128][64];   // 32KB
    // bijective XCD swizzle: 768 blocks = 8 XCD x 96
    int bid = blockIdx.x;
    int nf = (bid & 7) * 96 + (bid >> 3);
    int bx = nf & 31, byy = nf >> 5;
    int widx = byy >> 3;
    const _Float16* W = widx == 0 ? Wqp : widx == 1 ? Wkp : Wvp;
    const float* bias = widx == 0 ? bqp : widx == 1 ? bkp : bvp;
    float bscale = widx == 0 ? C2 : 1.0f;
    int tm = bx * 128;
    int tn = (byy & 7) * 128;
    int t = threadIdx.x;
    int wave = t >> 6, lane = t & 63;
    int wr = (wave >> 1) * 64, wc = (wave & 1) * 64;
    int lr = lane & 15, lg = lane >> 4;

    f32x4 acc[4][4] = {};

    int grow = lane >> 3;
    int gcol = (lane & 7) * 8;
    const _Float16* Aptr = A + (size_t)(tm + wave * 8 + grow) * DMODEL + gcol;
    const _Float16* Wptr = W + (size_t)(tn + wave * 8 + grow) * DMODEL + gcol;

    auto STAGE = [&](int buf, int k0) {
        #pragma unroll
        for (int i = 0; i < 4; ++i)
            GLL(Aptr + (size_t)i * 32 * DMODEL + k0, &As[buf][i * 32 + wave * 8][0]);
        #pragma unroll
        for (int i = 0; i < 4; ++i)
            GLL(Wptr + (size_t)i * 32 * DMODEL + k0, &Bs[buf][i * 32 + wave * 8][0]);
    };

    // prologue
    STAGE(0, 0);
    asm volatile("s_waitcnt vmcnt(0)" ::: "memory");
    __syncthreads();

    int cur = 0;
    for (int kt = 0; kt < 16; ++kt) {
        if (kt < 15) STAGE(cur ^ 1, (kt + 1) * 64);   // overlaps with compute below
        #pragma unroll
        for (int kk = 0; kk < 2; ++kk) {
            h8 af[4], bf[4];
            #pragma unroll
            for (int mi = 0; mi < 4; ++mi) af[mi] = *(const h8*)&As[cur][wr + mi * 16 + lr][kk * 32 + lg * 8];
            #pragma unroll
            for (int ni = 0; ni < 4; ++ni) bf[ni] = *(const h8*)&Bs[cur][wc + ni * 16 + lr][kk * 32 + lg * 8];
            #pragma unroll
            for (int mi = 0; mi < 4; ++mi)
                #pragma unroll
                for (int ni = 0; ni < 4; ++ni)
                    acc[mi][ni] = __builtin_amdgcn_mfma_f32_16x16x32_f16(af[mi], bf[ni], acc[mi][ni], 0, 0, 0);
        }
        // next tile staged + this buffer fully read -> single barrier per K-step
        asm volatile("s_waitcnt vmcnt(0) lgkmcnt(0)" ::: "memory");
        __syncthreads();
        cur ^= 1;
    }

    #pragma unroll
    for (int mi = 0; mi < 4; ++mi)
        #pragma unroll
        for (int ni = 0; ni < 4; ++ni) {
            int col = tn + wc + ni * 16 + lr;
            float bv = bias[col] * bscale;
            if (widx < 2) {
                _Float16* dst = widx == 0 ? qb : kb;
                #pragma unroll
                for (int j = 0; j < 4; ++j) {
                    int row = tm + wr + mi * 16 + lg * 4 + j;
                    dst[(size_t)row * DMODEL + col] = (_Float16)(acc[mi][ni][j] + bv);
                }
            } else {
                int row0 = tm + wr + mi * 16 + lg * 4;
                int b = row0 >> 11, n0 = row0 & 2047;
                h4 pk;
                #pragma unroll
                for (int j = 0; j < 4; ++j) pk[j] = (_Float16)(acc[mi][ni][j] + bv);
                *(h4*)&vt[((size_t)b * 1024 + col) * 2048 + n0] = pk;
            }
        }
}

// ---------------- AO GEMM: 64x128 tile, 2-phase double-buffered LDS ----------------
__global__ __launch_bounds__(256) void gemm_ao(
    const _Float16* __restrict__ A, const _Float16* __restrict__ W,
    const float* __restrict__ bias, float* __restrict__ C)
{
    __shared__ __align__(16) _Float16 As[2][64][64];    // 16KB
    __shared__ __align__(16) _Float16 Bs[2][128][64];   // 32KB
    // bijective XCD swizzle: 512 blocks = 8 XCD x 64
    int bid = blockIdx.x;
    int nf = (bid & 7) * 64 + (bid >> 3);
    int tm = (nf & 63) * 64;
    int tn = (nf >> 6) * 128;
    int t = threadIdx.x;
    int wave = t >> 6, lane = t & 63;
    int wr = (wave >> 1) * 32, wc = (wave & 1) * 64;
    int lr = lane & 15, lg = lane >> 4;

    f32x4 acc[2][4] = {};

    int grow = lane >> 3;
    int gcol = (lane & 7) * 8;
    const _Float16* Aptr = A + (size_t)(tm + wave * 8 + grow) * DMODEL + gcol;
    const _Float16* Wptr = W + (size_t)(tn + wave * 8 + grow) * DMODEL + gcol;

    auto STAGE = [&](int buf, int k0) {
        #pragma unroll
        for (int i = 0; i < 2; ++i)
            GLL(Aptr + (size_t)i * 32 * DMODEL + k0, &As[buf][i * 32 + wave * 8][0]);
        #pragma unroll
        for (int i = 0; i < 4; ++i)
            GLL(Wptr + (size_t)i * 32 * DMODEL + k0, &Bs[buf][i * 32 + wave * 8][0]);
    };

    STAGE(0, 0);
    asm volatile("s_waitcnt vmcnt(0)" ::: "memory");
    __syncthreads();

    int cur = 0;
    for (int kt = 0; kt < 16; ++kt) {
        if (kt < 15) STAGE(cur ^ 1, (kt + 1) * 64);
        #pragma unroll
        for (int kk = 0; kk < 2; ++kk) {
            h8 af[2], bf[4];
            #pragma unroll
            for (int mi = 0; mi < 2; ++mi) af[mi] = *(const h8*)&As[cur][wr + mi * 16 + lr][kk * 32 + lg * 8];
            #pragma unroll
            for (int ni = 0; ni < 4; ++ni) bf[ni] = *(const h8*)&Bs[cur][wc + ni * 16 + lr][kk * 32 + lg * 8];
            #pragma unroll
            for (int mi = 0; mi < 2; ++mi)
                #pragma unroll
                for (int ni = 0; ni < 4; ++ni)
                    acc[mi][ni] = __builtin_amdgcn_mfma_f32_16x16x32_f16(af[mi], bf[ni], acc[mi][ni], 0, 0, 0);
        }
        asm volatile("s_waitcnt vmcnt(0) lgkmcnt(0)" ::: "memory");
        __syncthreads();
        cur ^= 1;
    }

    #pragma unroll
    for (int mi = 0; mi < 2; ++mi)
        #pragma unroll
        for (int ni = 0; ni < 4; ++ni)
            #pragma unroll
            for (int j = 0; j < 4; ++j) {
                int row = tm + wr + mi * 16 + lg * 4 + j;
                int col = tn + wc + ni * 16 + lr;
                C[(size_t)row * DMODEL + col] = acc[mi][ni][j] + bias[col];
            }
}

// ---------------- flash attention v6 (unchanged from round 8) ----------------
#define KT 64

// byte offset into a [64 rows][128B] tile with XOR swizzle
#define SWZ(row, bytecol) ((row) * 128 + ((bytecol) ^ (((row) & 7) << 4)))

__global__ __launch_bounds__(512) void flash_kernel(
    const _Float16* __restrict__ Qb,   // [4096][1024], pre-scaled by C2
    const _Float16* __restrict__ Kb,   // [4096][1024]
    const _Float16* __restrict__ Vt,   // [2][1024][2048]
    const float* __restrict__ pb,      // [2][2048] log2-domain
    _Float16* __restrict__ AO)         // [4096][1024]
{
    __shared__ __align__(16) char KsB[2][8192];        // 16KB  K tiles [k][d]
    __shared__ __align__(16) char VsB[2][8192];        // 16KB  V^T tiles [d][k]
    __shared__ __align__(16) _Float16 Ps[8][16][72];   // 18KB  per-wave P (2-way floor)

    // bijective XCD swizzle: 512 blocks = 8 XCD x 64 -> 4 heads/XCD (K/V L2-resident)
    int bid = blockIdx.x + 16 * blockIdx.y;
    int nf = (bid & 7) * 64 + (bid >> 3);
    int qx = nf & 15, bh = nf >> 4;
    int b = bh >> 4, h = bh & 15;
    int q0 = qx * 128;
    int t = threadIdx.x, wave = t >> 6, lane = t & 63;
    int lr = lane & 15, lg = lane >> 4;

    const _Float16* Khead  = Kb + (size_t)b * NSEQ * DMODEL + h * HD;
    const _Float16* Vthead = Vt + ((size_t)b * 1024 + h * HD) * NSEQ;
    const float* pbb = pb + b * NSEQ;

    // Q fragment in registers: lane holds Q row q = q0 + wave*16 + lr
    const _Float16* Qrow = Qb + ((size_t)b * NSEQ + q0 + wave * 16 + lr) * DMODEL + h * HD;
    h8 qf0 = *(const h8*)&Qrow[lg * 8];
    h8 qf1 = *(const h8*)&Qrow[32 + lg * 8];

    const h8 vones = { (_Float16)1, (_Float16)1, (_Float16)1, (_Float16)1,
                       (_Float16)1, (_Float16)1, (_Float16)1, (_Float16)1 };

    float mrun = -INFINITY;               // running max for q = lr (dup across lg)
    f32x4 oacc[4] = {};                   // O[q = lg*4+j][d = ni*16+lr]
    f32x4 lsum = {};                      // row-sum for q = lg*4+j

    // staging: 512 threads x 1 GLL per matrix; linear dest, inverse-swizzled source chunk
    int srow = t >> 3;                    // row 0..63
    int schunk = (t & 7) ^ (srow & 7);    // global 16B chunk this thread loads
    const _Float16* Ksrc = Khead + (size_t)srow * DMODEL + schunk * 8;
    const _Float16* Vsrc = Vthead + (size_t)srow * NSEQ + schunk * 8;

    // prologue: stage tile 0 into buf 0
    GLL(Ksrc, KsB[0] + wave * 1024);
    GLL(Vsrc, VsB[0] + wave * 1024);
    asm volatile("s_waitcnt vmcnt(0)" ::: "memory");
    __syncthreads();

    int cur = 0;
    for (int kt = 0; kt < 32; ++kt) {
        int k0 = kt * KT;
        // issue next-tile staging (completes under this tile's LDS-read phase)
        if (kt < 31) {
            GLL(Ksrc + (size_t)(k0 + KT) * DMODEL, KsB[cur ^ 1] + wave * 1024);
            GLL(Vsrc + (k0 + KT), VsB[cur ^ 1] + wave * 1024);
        }
        const char* Kc = KsB[cur];
        const char* Vc = VsB[cur];

        // S^T = (C2*Q)K^T + bias : lane holds S[q=lr][k = ci*16 + lg*4 + j] (log2 domain)
        f32x4 s[4];
        #pragma unroll
        for (int ci = 0; ci < 4; ++ci)
            s[ci] = *(const f32x4*)&pbb[k0 + ci * 16 + lg * 4];
        __builtin_amdgcn_s_setprio(1);
        #pragma unroll
        for (int ci = 0; ci < 4; ++ci) {
            h8 kf = *(const h8*)(Kc + SWZ(ci * 16 + lr, lg * 16));
            s[ci] = __builtin_amdgcn_mfma_f32_16x16x32_f16(kf, qf0, s[ci], 0, 0, 0);
        }
        #pragma unroll
        for (int ci = 0; ci < 4; ++ci) {
            h8 kf = *(const h8*)(Kc + SWZ(ci * 16 + lr, 64 + lg * 16));
            s[ci] = __builtin_amdgcn_mfma_f32_16x16x32_f16(kf, qf1, s[ci], 0, 0, 0);
        }
        __builtin_amdgcn_s_setprio(0);

        // V fragments -> registers (last LDS reads of buf[cur])
        h8 vf[2][4];
        #pragma unroll
        for (int kb = 0; kb < 2; ++kb)
            #pragma unroll
            for (int ni = 0; ni < 4; ++ni)
                vf[kb][ni] = *(const h8*)(Vc + SWZ(ni * 16 + lr, kb * 64 + lg * 16));

        // EARLY barrier: buf[cur] fully consumed; next tile staged. Post-barrier work
        // is register-only, so waves de-lockstep and overlap across tiles.
        asm volatile("s_waitcnt vmcnt(0) lgkmcnt(0)" ::: "memory");
        __syncthreads();
        cur ^= 1;

        // row max (lane-local 16 + cross-lg)
        float sm = s[0][0];
        #pragma unroll
        for (int ci = 0; ci < 4; ++ci)
            #pragma unroll
            for (int j = 0; j < 4; ++j) sm = fmaxf(sm, s[ci][j]);
        sm = fmaxf(sm, __shfl_xor(sm, 16));
        sm = fmaxf(sm, __shfl_xor(sm, 32));

        bool need = __any(sm > mrun);
        float newm = need ? fmaxf(mrun, sm) : mrun;

        // P = exp2(s - newm) -> packed f16 (cvt_pkrtz) -> per-wave LDS
        #pragma unroll
        for (int ci = 0; ci < 4; ++ci) {
            fp16x2 a = __builtin_amdgcn_cvt_pkrtz(__builtin_amdgcn_exp2f(s[ci][0] - newm),
                                                  __builtin_amdgcn_exp2f(s[ci][1] - newm));
            fp16x2 b2 = __builtin_amdgcn_cvt_pkrtz(__builtin_amdgcn_exp2f(s[ci][2] - newm),
                                                   __builtin_amdgcn_exp2f(s[ci][3] - newm));
            union { fp16x2 hh[2]; uint2 u; } pk;
            pk.hh[0] = a; pk.hh[1] = b2;
            *(uint2*)&Ps[wave][lr][ci * 16 + lg * 4] = pk.u;
        }

        // rescale O (and sum) only when the max grew (wave-uniform branch)
        if (need) {
            float fs = __builtin_amdgcn_exp2f(mrun - newm);
            mrun = newm;
            #pragma unroll
            for (int j = 0; j < 4; ++j) {
                float fsj = __shfl(fs, (lane & 48) | (lg * 4 + j), 64);
                #pragma unroll
                for (int ni = 0; ni < 4; ++ni) oacc[ni][j] *= fsj;
                lsum[j] *= fsj;
            }
        }

        asm volatile("s_waitcnt lgkmcnt(0)" ::: "memory");
        __builtin_amdgcn_sched_barrier(0);

        // O += P @ V ; lsum += P @ 1
        __builtin_amdgcn_s_setprio(1);
        #pragma unroll
        for (int kb = 0; kb < 2; ++kb) {
            h8 pa = *(const h8*)&Ps[wave][lr][kb * 32 + lg * 8];
            #pragma unroll
            for (int ni = 0; ni < 4; ++ni)
                oacc[ni] = __builtin_amdgcn_mfma_f32_16x16x32_f16(pa, vf[kb][ni], oacc[ni], 0, 0, 0);
            lsum = __builtin_amdgcn_mfma_f32_16x16x32_f16(pa, vones, lsum, 0, 0, 0);
        }
        __builtin_amdgcn_s_setprio(0);
    }

    // epilogue: divide by row-sum (already in oacc layout), write out
    #pragma unroll
    for (int j = 0; j < 4; ++j) {
        float inv = 1.0f / lsum[j];
        int row = q0 + wave * 16 + lg * 4 + j;
        #pragma unroll
        for (int ni = 0; ni < 4; ++ni)
            AO[((size_t)b * NSEQ + row) * DMODEL + h * HD + ni * 16 + lr] = (_Float16)(oacc[ni][j] * inv);
    }
}

// ---------------- launcher ----------------
extern "C" void kernel_launch(void* const* d_in, const int* in_sizes, int n_in,
                              void* d_out, int out_size, void* d_ws, size_t ws_size,
                              hipStream_t stream) {
    const float* h    = (const float*)d_in[0];
    const float* prob = (const float*)d_in[1];
    const float* Wq   = (const float*)d_in[2];
    const float* bq   = (const float*)d_in[3];
    const float* Wk   = (const float*)d_in[4];
    const float* bk   = (const float*)d_in[5];
    const float* Wv   = (const float*)d_in[6];
    const float* bv   = (const float*)d_in[7];
    const float* Wo   = (const float*)d_in[8];
    const float* bo   = (const float*)d_in[9];
    const float* pbs  = (const float*)d_in[10];

    char* ws = (char*)d_ws;
    _Float16* hpe  = (_Float16*)(ws + OFF_HPE);
    _Float16* wq16 = (_Float16*)(ws + OFF_WQ);
    _Float16* wk16 = (_Float16*)(ws + OFF_WK);
    _Float16* wv16 = (_Float16*)(ws + OFF_WV);
    _Float16* wo16 = (_Float16*)(ws + OFF_WO);
    _Float16* qb   = (_Float16*)(ws + OFF_Q);
    _Float16* kb16 = (_Float16*)(ws + OFF_K);
    _Float16* vt   = (_Float16*)(ws + OFF_VT);
    _Float16* ao   = (_Float16*)(ws + OFF_AO);
    float*    pbuf = (float*)(ws + OFF_PB);

    prep_kernel<<<dim3(6160), dim3(256), 0, stream>>>(
        h, hpe, Wq, Wk, Wv, Wo, wq16, wk16, wv16, wo16, prob, pbs, pbuf);

    gemm_qkv<<<dim3(768), dim3(256), 0, stream>>>(hpe, wq16, wk16, wv16, bq, bk, bv, qb, kb16, vt);

    flash_kernel<<<dim3(16, 32), dim3(512), 0, stream>>>(qb, kb16, vt, pbuf, ao);

    gemm_ao<<<dim3(512), dim3(256), 0, stream>>>(ao, wo16, bo, (float*)d_out);
}

// Round 10
// 227.274 us; speedup vs baseline: 1.0386x; 1.0386x over previous
//
#include <hip/hip_runtime.h>

typedef _Float16 h8 __attribute__((ext_vector_type(8)));
typedef _Float16 h4 __attribute__((ext_vector_type(4)));
typedef __fp16 fp16x2 __attribute__((ext_vector_type(2)));
typedef float f32x4 __attribute__((ext_vector_type(4)));

#define NSEQ 2048
#define DMODEL 1024
#define HD 64
#define C2 0.1803368801111244f   // 0.125 * log2(e), folded into Wq/bq

// ---------------- workspace layout (bytes) ----------------
#define OFF_HPE  (size_t)0           // 4096x1024 f16 = 8MB
#define OFF_WQ   (size_t)8388608     // 1024x1024 f16 = 2MB (pre-scaled by C2)
#define OFF_WK   (size_t)10485760
#define OFF_WV   (size_t)12582912
#define OFF_WO   (size_t)14680064
#define OFF_Q    (size_t)16777216    // 4096x1024 f16 = 8MB (Q pre-scaled by C2)
#define OFF_K    (size_t)25165824
#define OFF_VT   (size_t)33554432    // [2][1024][2048] f16 = 8MB (V^T per head)
#define OFF_AO   (size_t)41943040    // 4096x1024 f16 = 8MB
#define OFF_PB   (size_t)50331648    // [2][2048] f32 (log2-domain bias)

#define GLL(g, l) __builtin_amdgcn_global_load_lds( \
    (const __attribute__((address_space(1))) unsigned int*)(const void*)(g), \
    (__attribute__((address_space(3))) unsigned int*)(l), 16, 0, 0)

// ---------------- fused prep kernel (unchanged) ----------------
__global__ void prep_kernel(const float* __restrict__ h, _Float16* __restrict__ hpe,
                            const float* __restrict__ w0, const float* __restrict__ w1,
                            const float* __restrict__ w2, const float* __restrict__ w3,
                            _Float16* __restrict__ d0, _Float16* __restrict__ d1,
                            _Float16* __restrict__ d2, _Float16* __restrict__ d3,
                            const float* __restrict__ probs, const float* __restrict__ pbs,
                            float* __restrict__ pb) {
    int idx = blockIdx.x * blockDim.x + threadIdx.x;
    if (idx < 524288) {
        int row = idx >> 7;
        int c8 = (idx & 127) * 8;
        int n = row & (NSEQ - 1);
        const float kL = -0.025952563241307517f;           // -log2(10000)/512
        const float kInv2Pi = 0.15915494309189535f;
        union { float4 f4[2]; float f[8]; } in;
        in.f4[0] = *(const float4*)&h[(size_t)row * DMODEL + c8];
        in.f4[1] = *(const float4*)&h[(size_t)row * DMODEL + c8 + 4];
        union { _Float16 hh[8]; uint4 u; } out;
        #pragma unroll
        for (int p = 0; p < 4; ++p) {
            int i2 = (c8 >> 1) + p;
            float div = __builtin_amdgcn_exp2f((float)i2 * kL);
            float rev = (float)n * div * kInv2Pi;
            float rf = __builtin_amdgcn_fractf(rev);
            float s = __builtin_amdgcn_sinf(rf);
            float c = __builtin_amdgcn_cosf(rf);
            out.hh[2 * p]     = (_Float16)(in.f[2 * p] + s);
            out.hh[2 * p + 1] = (_Float16)(in.f[2 * p + 1] + c);
        }
        *(uint4*)&hpe[(size_t)row * DMODEL + c8] = out.u;
    } else if (idx < 1572864) {
        int j = idx - 524288;
        int which = j >> 18, i2 = j & 262143;
        const float* s = which == 0 ? w0 : which == 1 ? w1 : which == 2 ? w2 : w3;
        _Float16* d    = which == 0 ? d0 : which == 1 ? d1 : which == 2 ? d2 : d3;
        float sc = which == 0 ? C2 : 1.0f;
        float4 v = ((const float4*)s)[i2];
        union { _Float16 hh[4]; uint2 u; } o;
        o.hh[0] = (_Float16)(v.x * sc); o.hh[1] = (_Float16)(v.y * sc);
        o.hh[2] = (_Float16)(v.z * sc); o.hh[3] = (_Float16)(v.w * sc);
        ((uint2*)d)[i2] = o.u;
    } else if (idx < 1576960) {
        int k = idx - 1572864;
        pb[k] = pbs[0] * log2f(probs[k] + 1e-8f);
    }
}

// ---------------- fused QKV GEMM: 128x128, dbuf + COUNTED vmcnt + raw barriers ----------------
// grid 768; per-XCD: 4 A-panels resident (byy inner). byy 0-7 Q, 8-15 K, 16-23 V^T.
__global__ __launch_bounds__(256) void gemm_qkv(
    const _Float16* __restrict__ A,
    const _Float16* __restrict__ Wqp, const _Float16* __restrict__ Wkp, const _Float16* __restrict__ Wvp,
    const float* __restrict__ bqp, const float* __restrict__ bkp, const float* __restrict__ bvp,
    _Float16* __restrict__ qb, _Float16* __restrict__ kb, _Float16* __restrict__ vt)
{
    __shared__ __align__(16) _Float16 As[2][128][64];   // 32KB
    __shared__ __align__(16) _Float16 Bs[2][128][64];   // 32KB
    // L2-friendly XCD map: xcd = bid&7 (HW round-robin); A-panel varies slowest
    int xcd = blockIdx.x & 7;
    int local = blockIdx.x >> 3;            // 0..95
    int bx = xcd * 4 + local / 24;          // 0..31  (4 A-panels per XCD)
    int byy = local % 24;                   // 0..23  (inner: W streams, A resident)
    int widx = byy >> 3;
    const _Float16* W = widx == 0 ? Wqp : widx == 1 ? Wkp : Wvp;
    const float* bias = widx == 0 ? bqp : widx == 1 ? bkp : bvp;
    float bscale = widx == 0 ? C2 : 1.0f;
    int tm = bx * 128;
    int tn = (byy & 7) * 128;
    int t = threadIdx.x;
    int wave = t >> 6, lane = t & 63;
    int wr = (wave >> 1) * 64, wc = (wave & 1) * 64;
    int lr = lane & 15, lg = lane >> 4;

    f32x4 acc[4][4] = {};

    int grow = lane >> 3;
    int gcol = (lane & 7) * 8;
    const _Float16* Aptr = A + (size_t)(tm + wave * 8 + grow) * DMODEL + gcol;
    const _Float16* Wptr = W + (size_t)(tn + wave * 8 + grow) * DMODEL + gcol;

    auto STAGE = [&](int buf, int k0) {
        #pragma unroll
        for (int i = 0; i < 4; ++i)
            GLL(Aptr + (size_t)i * 32 * DMODEL + k0, &As[buf][i * 32 + wave * 8][0]);
        #pragma unroll
        for (int i = 0; i < 4; ++i)
            GLL(Wptr + (size_t)i * 32 * DMODEL + k0, &Bs[buf][i * 32 + wave * 8][0]);
    };

    STAGE(0, 0);                                    // 8 loads in flight
    int cur = 0;
    for (int kt = 0; kt < 16; ++kt) {
        STAGE(cur ^ 1, ((kt + 1) & 15) * 64);       // +8 newest (wraps at end; harmless)
        // wait until only the 8 newest remain -> buf[cur] complete; loads keep flying
        asm volatile("s_waitcnt vmcnt(8)" ::: "memory");
        __builtin_amdgcn_s_barrier();               // raw barrier: no hidden vmcnt(0) drain
        #pragma unroll
        for (int kk = 0; kk < 2; ++kk) {
            h8 af[4], bf[4];
            #pragma unroll
            for (int mi = 0; mi < 4; ++mi) af[mi] = *(const h8*)&As[cur][wr + mi * 16 + lr][kk * 32 + lg * 8];
            #pragma unroll
            for (int ni = 0; ni < 4; ++ni) bf[ni] = *(const h8*)&Bs[cur][wc + ni * 16 + lr][kk * 32 + lg * 8];
            #pragma unroll
            for (int mi = 0; mi < 4; ++mi)
                #pragma unroll
                for (int ni = 0; ni < 4; ++ni)
                    acc[mi][ni] = __builtin_amdgcn_mfma_f32_16x16x32_f16(af[mi], bf[ni], acc[mi][ni], 0, 0, 0);
        }
        // all ds_reads of buf[cur] retired -> next iter may overwrite it
        asm volatile("s_waitcnt lgkmcnt(0)" ::: "memory");
        __builtin_amdgcn_sched_barrier(0);
        __builtin_amdgcn_s_barrier();
        cur ^= 1;
    }

    #pragma unroll
    for (int mi = 0; mi < 4; ++mi)
        #pragma unroll
        for (int ni = 0; ni < 4; ++ni) {
            int col = tn + wc + ni * 16 + lr;
            float bv = bias[col] * bscale;
            if (widx < 2) {
                _Float16* dst = widx == 0 ? qb : kb;
                #pragma unroll
                for (int j = 0; j < 4; ++j) {
                    int row = tm + wr + mi * 16 + lg * 4 + j;
                    dst[(size_t)row * DMODEL + col] = (_Float16)(acc[mi][ni][j] + bv);
                }
            } else {
                int row0 = tm + wr + mi * 16 + lg * 4;
                int b = row0 >> 11, n0 = row0 & 2047;
                h4 pk;
                #pragma unroll
                for (int j = 0; j < 4; ++j) pk[j] = (_Float16)(acc[mi][ni][j] + bv);
                *(h4*)&vt[((size_t)b * 1024 + col) * 2048 + n0] = pk;
            }
        }
}

// ---------------- AO GEMM: 64x128, dbuf + COUNTED vmcnt + raw barriers ----------------
__global__ __launch_bounds__(256) void gemm_ao(
    const _Float16* __restrict__ A, const _Float16* __restrict__ W,
    const float* __restrict__ bias, float* __restrict__ C)
{
    __shared__ __align__(16) _Float16 As[2][64][64];    // 16KB
    __shared__ __align__(16) _Float16 Bs[2][128][64];   // 32KB
    // L2-friendly XCD map: 512 = 8 xcd x 64; tn inner (W-panel cycles, A resident)
    int xcd = blockIdx.x & 7;
    int local = blockIdx.x >> 3;            // 0..63
    int tm = (xcd * 8 + (local >> 3)) * 64;
    int tn = (local & 7) * 128;
    int t = threadIdx.x;
    int wave = t >> 6, lane = t & 63;
    int wr = (wave >> 1) * 32, wc = (wave & 1) * 64;
    int lr = lane & 15, lg = lane >> 4;

    f32x4 acc[2][4] = {};

    int grow = lane >> 3;
    int gcol = (lane & 7) * 8;
    const _Float16* Aptr = A + (size_t)(tm + wave * 8 + grow) * DMODEL + gcol;
    const _Float16* Wptr = W + (size_t)(tn + wave * 8 + grow) * DMODEL + gcol;

    auto STAGE = [&](int buf, int k0) {
        #pragma unroll
        for (int i = 0; i < 2; ++i)
            GLL(Aptr + (size_t)i * 32 * DMODEL + k0, &As[buf][i * 32 + wave * 8][0]);
        #pragma unroll
        for (int i = 0; i < 4; ++i)
            GLL(Wptr + (size_t)i * 32 * DMODEL + k0, &Bs[buf][i * 32 + wave * 8][0]);
    };

    STAGE(0, 0);                                    // 6 loads in flight
    int cur = 0;
    for (int kt = 0; kt < 16; ++kt) {
        STAGE(cur ^ 1, ((kt + 1) & 15) * 64);       // +6 newest
        asm volatile("s_waitcnt vmcnt(6)" ::: "memory");
        __builtin_amdgcn_s_barrier();
        #pragma unroll
        for (int kk = 0; kk < 2; ++kk) {
            h8 af[2], bf[4];
            #pragma unroll
            for (int mi = 0; mi < 2; ++mi) af[mi] = *(const h8*)&As[cur][wr + mi * 16 + lr][kk * 32 + lg * 8];
            #pragma unroll
            for (int ni = 0; ni < 4; ++ni) bf[ni] = *(const h8*)&Bs[cur][wc + ni * 16 + lr][kk * 32 + lg * 8];
            #pragma unroll
            for (int mi = 0; mi < 2; ++mi)
                #pragma unroll
                for (int ni = 0; ni < 4; ++ni)
                    acc[mi][ni] = __builtin_amdgcn_mfma_f32_16x16x32_f16(af[mi], bf[ni], acc[mi][ni], 0, 0, 0);
        }
        asm volatile("s_waitcnt lgkmcnt(0)" ::: "memory");
        __builtin_amdgcn_sched_barrier(0);
        __builtin_amdgcn_s_barrier();
        cur ^= 1;
    }

    #pragma unroll
    for (int mi = 0; mi < 2; ++mi)
        #pragma unroll
        for (int ni = 0; ni < 4; ++ni)
            #pragma unroll
            for (int j = 0; j < 4; ++j) {
                int row = tm + wr + mi * 16 + lg * 4 + j;
                int col = tn + wc + ni * 16 + lr;
                C[(size_t)row * DMODEL + col] = acc[mi][ni][j] + bias[col];
            }
}

// ---------------- flash attention v6 (unchanged from round 8) ----------------
#define KT 64

// byte offset into a [64 rows][128B] tile with XOR swizzle
#define SWZ(row, bytecol) ((row) * 128 + ((bytecol) ^ (((row) & 7) << 4)))

__global__ __launch_bounds__(512) void flash_kernel(
    const _Float16* __restrict__ Qb,   // [4096][1024], pre-scaled by C2
    const _Float16* __restrict__ Kb,   // [4096][1024]
    const _Float16* __restrict__ Vt,   // [2][1024][2048]
    const float* __restrict__ pb,      // [2][2048] log2-domain
    _Float16* __restrict__ AO)         // [4096][1024]
{
    __shared__ __align__(16) char KsB[2][8192];        // 16KB  K tiles [k][d]
    __shared__ __align__(16) char VsB[2][8192];        // 16KB  V^T tiles [d][k]
    __shared__ __align__(16) _Float16 Ps[8][16][72];   // 18KB  per-wave P (2-way floor)

    // bijective XCD swizzle: 512 blocks = 8 XCD x 64 -> 4 heads/XCD (K/V L2-resident)
    int bid = blockIdx.x + 16 * blockIdx.y;
    int nf = (bid & 7) * 64 + (bid >> 3);
    int qx = nf & 15, bh = nf >> 4;
    int b = bh >> 4, h = bh & 15;
    int q0 = qx * 128;
    int t = threadIdx.x, wave = t >> 6, lane = t & 63;
    int lr = lane & 15, lg = lane >> 4;

    const _Float16* Khead  = Kb + (size_t)b * NSEQ * DMODEL + h * HD;
    const _Float16* Vthead = Vt + ((size_t)b * 1024 + h * HD) * NSEQ;
    const float* pbb = pb + b * NSEQ;

    // Q fragment in registers: lane holds Q row q = q0 + wave*16 + lr
    const _Float16* Qrow = Qb + ((size_t)b * NSEQ + q0 + wave * 16 + lr) * DMODEL + h * HD;
    h8 qf0 = *(const h8*)&Qrow[lg * 8];
    h8 qf1 = *(const h8*)&Qrow[32 + lg * 8];

    const h8 vones = { (_Float16)1, (_Float16)1, (_Float16)1, (_Float16)1,
                       (_Float16)1, (_Float16)1, (_Float16)1, (_Float16)1 };

    float mrun = -INFINITY;               // running max for q = lr (dup across lg)
    f32x4 oacc[4] = {};                   // O[q = lg*4+j][d = ni*16+lr]
    f32x4 lsum = {};                      // row-sum for q = lg*4+j

    // staging: 512 threads x 1 GLL per matrix; linear dest, inverse-swizzled source chunk
    int srow = t >> 3;                    // row 0..63
    int schunk = (t & 7) ^ (srow & 7);    // global 16B chunk this thread loads
    const _Float16* Ksrc = Khead + (size_t)srow * DMODEL + schunk * 8;
    const _Float16* Vsrc = Vthead + (size_t)srow * NSEQ + schunk * 8;

    // prologue: stage tile 0 into buf 0
    GLL(Ksrc, KsB[0] + wave * 1024);
    GLL(Vsrc, VsB[0] + wave * 1024);
    asm volatile("s_waitcnt vmcnt(0)" ::: "memory");
    __syncthreads();

    int cur = 0;
    for (int kt = 0; kt < 32; ++kt) {
        int k0 = kt * KT;
        // issue next-tile staging (completes under this tile's LDS-read phase)
        if (kt < 31) {
            GLL(Ksrc + (size_t)(k0 + KT) * DMODEL, KsB[cur ^ 1] + wave * 1024);
            GLL(Vsrc + (k0 + KT), VsB[cur ^ 1] + wave * 1024);
        }
        const char* Kc = KsB[cur];
        const char* Vc = VsB[cur];

        // S^T = (C2*Q)K^T + bias : lane holds S[q=lr][k = ci*16 + lg*4 + j] (log2 domain)
        f32x4 s[4];
        #pragma unroll
        for (int ci = 0; ci < 4; ++ci)
            s[ci] = *(const f32x4*)&pbb[k0 + ci * 16 + lg * 4];
        __builtin_amdgcn_s_setprio(1);
        #pragma unroll
        for (int ci = 0; ci < 4; ++ci) {
            h8 kf = *(const h8*)(Kc + SWZ(ci * 16 + lr, lg * 16));
            s[ci] = __builtin_amdgcn_mfma_f32_16x16x32_f16(kf, qf0, s[ci], 0, 0, 0);
        }
        #pragma unroll
        for (int ci = 0; ci < 4; ++ci) {
            h8 kf = *(const h8*)(Kc + SWZ(ci * 16 + lr, 64 + lg * 16));
            s[ci] = __builtin_amdgcn_mfma_f32_16x16x32_f16(kf, qf1, s[ci], 0, 0, 0);
        }
        __builtin_amdgcn_s_setprio(0);

        // V fragments -> registers (last LDS reads of buf[cur])
        h8 vf[2][4];
        #pragma unroll
        for (int kb = 0; kb < 2; ++kb)
            #pragma unroll
            for (int ni = 0; ni < 4; ++ni)
                vf[kb][ni] = *(const h8*)(Vc + SWZ(ni * 16 + lr, kb * 64 + lg * 16));

        // EARLY barrier: buf[cur] fully consumed; next tile staged. Post-barrier work
        // is register-only, so waves de-lockstep and overlap across tiles.
        asm volatile("s_waitcnt vmcnt(0) lgkmcnt(0)" ::: "memory");
        __syncthreads();
        cur ^= 1;

        // row max (lane-local 16 + cross-lg)
        float sm = s[0][0];
        #pragma unroll
        for (int ci = 0; ci < 4; ++ci)
            #pragma unroll
            for (int j = 0; j < 4; ++j) sm = fmaxf(sm, s[ci][j]);
        sm = fmaxf(sm, __shfl_xor(sm, 16));
        sm = fmaxf(sm, __shfl_xor(sm, 32));

        bool need = __any(sm > mrun);
        float newm = need ? fmaxf(mrun, sm) : mrun;

        // P = exp2(s - newm) -> packed f16 (cvt_pkrtz) -> per-wave LDS
        #pragma unroll
        for (int ci = 0; ci < 4; ++ci) {
            fp16x2 a = __builtin_amdgcn_cvt_pkrtz(__builtin_amdgcn_exp2f(s[ci][0] - newm),
                                                  __builtin_amdgcn_exp2f(s[ci][1] - newm));
            fp16x2 b2 = __builtin_amdgcn_cvt_pkrtz(__builtin_amdgcn_exp2f(s[ci][2] - newm),
                                                   __builtin_amdgcn_exp2f(s[ci][3] - newm));
            union { fp16x2 hh[2]; uint2 u; } pk;
            pk.hh[0] = a; pk.hh[1] = b2;
            *(uint2*)&Ps[wave][lr][ci * 16 + lg * 4] = pk.u;
        }

        // rescale O (and sum) only when the max grew (wave-uniform branch)
        if (need) {
            float fs = __builtin_amdgcn_exp2f(mrun - newm);
            mrun = newm;
            #pragma unroll
            for (int j = 0; j < 4; ++j) {
                float fsj = __shfl(fs, (lane & 48) | (lg * 4 + j), 64);
                #pragma unroll
                for (int ni = 0; ni < 4; ++ni) oacc[ni][j] *= fsj;
                lsum[j] *= fsj;
            }
        }

        asm volatile("s_waitcnt lgkmcnt(0)" ::: "memory");
        __builtin_amdgcn_sched_barrier(0);

        // O += P @ V ; lsum += P @ 1
        __builtin_amdgcn_s_setprio(1);
        #pragma unroll
        for (int kb = 0; kb < 2; ++kb) {
            h8 pa = *(const h8*)&Ps[wave][lr][kb * 32 + lg * 8];
            #pragma unroll
            for (int ni = 0; ni < 4; ++ni)
                oacc[ni] = __builtin_amdgcn_mfma_f32_16x16x32_f16(pa, vf[kb][ni], oacc[ni], 0, 0, 0);
            lsum = __builtin_amdgcn_mfma_f32_16x16x32_f16(pa, vones, lsum, 0, 0, 0);
        }
        __builtin_amdgcn_s_setprio(0);
    }

    // epilogue: divide by row-sum (already in oacc layout), write out
    #pragma unroll
    for (int j = 0; j < 4; ++j) {
        float inv = 1.0f / lsum[j];
        int row = q0 + wave * 16 + lg * 4 + j;
        #pragma unroll
        for (int ni = 0; ni < 4; ++ni)
            AO[((size_t)b * NSEQ + row) * DMODEL + h * HD + ni * 16 + lr] = (_Float16)(oacc[ni][j] * inv);
    }
}

// ---------------- launcher ----------------
extern "C" void kernel_launch(void* const* d_in, const int* in_sizes, int n_in,
                              void* d_out, int out_size, void* d_ws, size_t ws_size,
                              hipStream_t stream) {
    const float* h    = (const float*)d_in[0];
    const float* prob = (const float*)d_in[1];
    const float* Wq   = (const float*)d_in[2];
    const float* bq   = (const float*)d_in[3];
    const float* Wk   = (const float*)d_in[4];
    const float* bk   = (const float*)d_in[5];
    const float* Wv   = (const float*)d_in[6];
    const float* bv   = (const float*)d_in[7];
    const float* Wo   = (const float*)d_in[8];
    const float* bo   = (const float*)d_in[9];
    const float* pbs  = (const float*)d_in[10];

    char* ws = (char*)d_ws;
    _Float16* hpe  = (_Float16*)(ws + OFF_HPE);
    _Float16* wq16 = (_Float16*)(ws + OFF_WQ);
    _Float16* wk16 = (_Float16*)(ws + OFF_WK);
    _Float16* wv16 = (_Float16*)(ws + OFF_WV);
    _Float16* wo16 = (_Float16*)(ws + OFF_WO);
    _Float16* qb   = (_Float16*)(ws + OFF_Q);
    _Float16* kb16 = (_Float16*)(ws + OFF_K);
    _Float16* vt   = (_Float16*)(ws + OFF_VT);
    _Float16* ao   = (_Float16*)(ws + OFF_AO);
    float*    pbuf = (float*)(ws + OFF_PB);

    prep_kernel<<<dim3(6160), dim3(256), 0, stream>>>(
        h, hpe, Wq, Wk, Wv, Wo, wq16, wk16, wv16, wo16, prob, pbs, pbuf);

    gemm_qkv<<<dim3(768), dim3(256), 0, stream>>>(hpe, wq16, wk16, wv16, bq, bk, bv, qb, kb16, vt);

    flash_kernel<<<dim3(16, 32), dim3(512), 0, stream>>>(qb, kb16, vt, pbuf, ao);

    gemm_ao<<<dim3(512), dim3(256), 0, stream>>>(ao, wo16, bo, (float*)d_out);
}